// Round 1
// baseline (114.895 us; speedup 1.0000x reference)
//
#include <hip/hip_runtime.h>
#include <hip/hip_bf16.h>

// SimpleRNN(tanh, return final h) + Dense(5) + softmax, fused single kernel.
// B=8192, T=187, D=1, H=128, C=5.
//
// Transposed recurrence: h_pre^T = U^T @ h^T  (M=j, N=batch, K=i) with
// mfma_f32_16x16x32_bf16. D-fragment layout == next-step B-fragment layout
// (both: idx = 4*(lane>>4)+sub, col = lane&15), so no cross-lane movement.
// 4 waves/block split H (32 j each); h-fragments exchanged via LDS each step.
// U split into hi+lo bf16 (error compensation); x*W+b accumulated in fp32.

#define BT 8192
#define TS 187
#define HD 128
#define NC 5

typedef float  f32x4  __attribute__((ext_vector_type(4)));
typedef __bf16 bf16x8 __attribute__((ext_vector_type(8)));

__device__ __forceinline__ float tanh_fast(float v) {
    // tanh(v) = 1 - 2/(exp(2v)+1); exact at +-inf, no NaN (rcp(inf)=0).
    float e = __expf(2.0f * v);
    float r = __builtin_amdgcn_rcpf(e + 1.0f);
    return fmaf(-2.0f, r, 1.0f);
}

__global__ __launch_bounds__(256, 2)
void rnn_fused(const float* __restrict__ xg, const float* __restrict__ wg,
               const float* __restrict__ ug, const float* __restrict__ bg,
               const float* __restrict__ wdg, const float* __restrict__ bdg,
               float* __restrict__ outg)
{
    __shared__ bf16x8 xbuf[2][4][64];   // [dbuf][wave][lane] h-frag exchange, 8KB
    __shared__ float  hsm[HD][16];      // final h for the head, 8KB
    __shared__ float  lg[16][NC];

    const int tid  = threadIdx.x;
    const int w    = tid >> 6;          // wave 0..3, owns j in [32w, 32w+32)
    const int lane = tid & 63;
    const int l15  = lane & 15;         // batch-col within tile / j-col for A
    const int l4   = lane >> 4;         // 0..3
    const int b0   = blockIdx.x * 16;   // batch group

    // ---- preload U^T fragments (hi+lo split), W, bias ----
    // A-frag (M=j,K=i): m = l15 -> j = 32w+16jt+l15 ;
    // elem e -> i = 32T + 16*(e>>2) + 4*l4 + (e&3)
    bf16x8 ufh[2][4], ufl[2][4];
    #pragma unroll
    for (int jt = 0; jt < 2; ++jt) {
        const int j = 32*w + 16*jt + l15;
        #pragma unroll
        for (int T = 0; T < 4; ++T) {
            #pragma unroll
            for (int e = 0; e < 8; ++e) {
                const int i = 32*T + 16*(e>>2) + 4*l4 + (e&3);
                float u = ug[i*HD + j];
                __bf16 uh = (__bf16)u;
                ufh[jt][T][e] = uh;
                ufl[jt][T][e] = (__bf16)(u - (float)uh);
            }
        }
    }
    float wv0[4], wv1[4], bv0[4], bv1[4];
    #pragma unroll
    for (int q = 0; q < 4; ++q) {
        const int j0 = 32*w + 4*l4 + q;          // jt=0 rows
        wv0[q] = wg[j0];      bv0[q] = bg[j0];
        wv1[q] = wg[j0 + 16]; bv1[q] = bg[j0 + 16];
    }

    // ---- state: h fragments (B-operand layout), start at h0 = 0 ----
    bf16x8 hfr[4];
    #pragma unroll
    for (int t = 0; t < 4; ++t) {
        #pragma unroll
        for (int e = 0; e < 8; ++e) hfr[t][e] = (__bf16)0.0f;
    }

    const float* xrow = xg + (long)(b0 + l15) * TS;
    float xv = xrow[0];

    f32x4 acc0, acc1;   // post-tanh h persists here for the epilogue

    for (int s = 0; s < TS; ++s) {
        // prefetch next x (no deps -> issues early, hidden under MFMAs)
        float xnext = (s + 1 < TS) ? xrow[s + 1] : 0.0f;

        // fp32 init: x*W + b
        #pragma unroll
        for (int q = 0; q < 4; ++q) {
            acc0[q] = fmaf(xv, wv0[q], bv0[q]);
            acc1[q] = fmaf(xv, wv1[q], bv1[q]);
        }

        // h_pre^T += U^T h^T  (hi + lo compensation)
        #pragma unroll
        for (int T = 0; T < 4; ++T) {
            acc0 = __builtin_amdgcn_mfma_f32_16x16x32_bf16(ufh[0][T], hfr[T], acc0, 0, 0, 0);
            acc1 = __builtin_amdgcn_mfma_f32_16x16x32_bf16(ufh[1][T], hfr[T], acc1, 0, 0, 0);
            acc0 = __builtin_amdgcn_mfma_f32_16x16x32_bf16(ufl[0][T], hfr[T], acc0, 0, 0, 0);
            acc1 = __builtin_amdgcn_mfma_f32_16x16x32_bf16(ufl[1][T], hfr[T], acc1, 0, 0, 0);
        }

        // tanh (in place; last iteration's values feed the head)
        #pragma unroll
        for (int q = 0; q < 4; ++q) {
            acc0[q] = tanh_fast(acc0[q]);
            acc1[q] = tanh_fast(acc1[q]);
        }

        // pack own fragment: elem e -> hn[jt = e>>2][q = e&3]
        bf16x8 F;
        #pragma unroll
        for (int q = 0; q < 4; ++q) {
            F[q]     = (__bf16)acc0[q];
            F[4 + q] = (__bf16)acc1[q];
        }

        // exchange (double-buffered, single barrier per step is race-free:
        // reads of buf[s&1] are consumed before the writer's next barrier)
        xbuf[s & 1][w][lane] = F;
        __syncthreads();
        #pragma unroll
        for (int t = 0; t < 4; ++t) hfr[t] = xbuf[s & 1][t][lane];

        xv = xnext;
    }

    // ---- head: logits = h @ Wd + bd ; softmax over 5 ----
    #pragma unroll
    for (int q = 0; q < 4; ++q) {
        hsm[32*w +      4*l4 + q][l15] = acc0[q];
        hsm[32*w + 16 + 4*l4 + q][l15] = acc1[q];
    }
    __syncthreads();

    if (tid < 16 * NC) {
        const int bi = tid / NC, c = tid % NC;
        float a = bdg[c];
        for (int j = 0; j < HD; ++j) a = fmaf(hsm[j][bi], wdg[j*NC + c], a);
        lg[bi][c] = a;
    }
    __syncthreads();

    if (tid < 16) {
        float m = lg[tid][0];
        #pragma unroll
        for (int c = 1; c < NC; ++c) m = fmaxf(m, lg[tid][c]);
        float e[NC], ssum = 0.0f;
        #pragma unroll
        for (int c = 0; c < NC; ++c) { e[c] = __expf(lg[tid][c] - m); ssum += e[c]; }
        const float rs = 1.0f / ssum;
        #pragma unroll
        for (int c = 0; c < NC; ++c) outg[(long)(b0 + tid)*NC + c] = e[c] * rs;
    }
}

extern "C" void kernel_launch(void* const* d_in, const int* in_sizes, int n_in,
                              void* d_out, int out_size, void* d_ws, size_t ws_size,
                              hipStream_t stream) {
    const float* x  = (const float*)d_in[0];  // [8192][187][1]
    const float* W  = (const float*)d_in[1];  // [1][128]
    const float* U  = (const float*)d_in[2];  // [128][128]
    const float* b  = (const float*)d_in[3];  // [128]
    const float* Wd = (const float*)d_in[4];  // [128][5]
    const float* bd = (const float*)d_in[5];  // [5]
    float* out = (float*)d_out;               // [8192][5]

    rnn_fused<<<BT / 16, 256, 0, stream>>>(x, W, U, b, Wd, bd, out);
}